// Round 11
// baseline (355.693 us; speedup 1.0000x reference)
//
#include <hip/hip_runtime.h>

#define NN 50000
#define EE 800000
#define IND 128
#define EDD 32
#define ODD 16
#define NH 4
#define HD 64
#define NEG_SLOPE 0.2f
#define NBLK ((NN + 255) / 256)   // 196 scan blocks
#define NODE_BLKS ((NN + 63) / 64) // 782 node blocks

typedef float  f32x4 __attribute__((ext_vector_type(4)));
typedef int    i32x2 __attribute__((ext_vector_type(2)));
typedef int    i32x4 __attribute__((ext_vector_type(4)));
typedef _Float16 f16x8 __attribute__((ext_vector_type(8)));

union h2i { int i; _Float16 h[2]; };

// ---------------- init+prep fused: deg=0; Wt transpose; w_ee fold ----------
__global__ __launch_bounds__(256)
void k_init_prep(int* __restrict__ deg, const float* __restrict__ W_fc,
                 const float* __restrict__ W_edge, const float* __restrict__ attn_e,
                 float* __restrict__ Wt, float* __restrict__ w_ee) {
    int i = blockIdx.x * 256 + threadIdx.x;
    if (i < NN) deg[i] = 0;
    if (i < HD * IND) {
        int k = i >> 6, j = i & 63;
        Wt[i] = W_fc[j * IND + k];
    }
    if (i < NH * EDD) {
        int h = i >> 5, k = i & 31;
        float s = 0.f;
        for (int d = 0; d < ODD; ++d)
            s += W_edge[(h * ODD + d) * EDD + k] * attn_e[h * ODD + d];
        w_ee[i] = s;
    }
}

// ------- node projection, LDS-staged cooperative ----------------------------
// Block = 64 rows (32KB LDS). Stage: 8 coalesced nt loads/thread (4KB
// contiguous per wave instruction) -> kills the 64-segment fan-out of the
// row-per-thread layout (feat read ONCE from HBM). XOR-swizzled columns
// (c ^ (r&7)) -> ds_read_b128 at the irreducible 8-clk floor, no 16-way
// same-bank conflict. Compute: thread t = row (t&63) x head (t>>6), 16 accs.
__global__ __launch_bounds__(256)
void k_node(const float* __restrict__ feat, const float* __restrict__ Wt,
            const float* __restrict__ attn_h, const float* __restrict__ attn_t,
            _Float16* __restrict__ feat_h, float* __restrict__ eh,
            float* __restrict__ et) {
    __shared__ f32x4 buf[64 * 32];          // 32 KB
    int t = threadIdx.x;
    long n0 = (long)blockIdx.x * 64;
    int nrow = (n0 + 64 <= NN) ? 64 : (int)(NN - n0);
    int totj = nrow * 32;
    const f32x4* g = (const f32x4*)feat + n0 * 32;
#pragma unroll
    for (int i = 0; i < 8; ++i) {
        int j = t + i * 256;
        if (j < totj) {
            f32x4 v = __builtin_nontemporal_load(g + j);
            int r = j >> 5, c = j & 31;
            buf[r * 32 + (c ^ (r & 7))] = v;
        }
    }
    __syncthreads();
    int r = t & 63, qt = t >> 6;            // row slot, head
    if (n0 + r >= NN) return;
    const int jbase = qt * 16;
    f32x4 row[32];
#pragma unroll
    for (int q = 0; q < 32; ++q) row[q] = buf[r * 32 + (q ^ (r & 7))];
    float acc[16];
#pragma unroll
    for (int j = 0; j < 16; ++j) acc[j] = 0.f;
#pragma unroll
    for (int k0 = 0; k0 < 32; ++k0) {
        float f[4] = {row[k0][0], row[k0][1], row[k0][2], row[k0][3]};
#pragma unroll
        for (int kk = 0; kk < 4; ++kk) {
            const float* w = Wt + (k0 * 4 + kk) * HD + jbase;  // wave-uniform
#pragma unroll
            for (int j = 0; j < 16; ++j) acc[j] += f[kk] * w[j];
        }
    }
    long n = n0 + r;
    // fp16 pack: 16 halves = 2 x 16B stores
    f16x8* d8 = (f16x8*)(feat_h + n * HD + jbase);
#pragma unroll
    for (int q = 0; q < 2; ++q) {
        f16x8 v;
#pragma unroll
        for (int j = 0; j < 8; ++j) v[j] = (_Float16)acc[q * 8 + j];
        d8[q] = v;
    }
    float sh = 0.f, st = 0.f;
#pragma unroll
    for (int d = 0; d < ODD; ++d) {
        sh += acc[d] * attn_h[qt * ODD + d];
        st += acc[d] * attn_t[qt * ODD + d];
    }
    eh[n * 4 + qt] = sh;                    // [N][4] layout
    et[n * 4 + qt] = st;
}

// ---------------- histogram of dst + per-edge rank --------------------------
__global__ __launch_bounds__(256)
void k_hist(const int* __restrict__ dst, int* __restrict__ deg, int* __restrict__ rank) {
    int e = blockIdx.x * 256 + threadIdx.x;
    if (e < EE) rank[e] = atomicAdd(&deg[dst[e]], 1);
}

// ---------------- two-level exclusive scan of deg -> offs -------------------
__global__ __launch_bounds__(256)
void k_scan1(const int* __restrict__ deg, int* __restrict__ offs, int* __restrict__ part) {
    __shared__ int s[256];
    int t = threadIdx.x, i = blockIdx.x * 256 + t;
    int v = (i < NN) ? deg[i] : 0;
    s[t] = v;
    __syncthreads();
#pragma unroll
    for (int o = 1; o < 256; o <<= 1) {
        int u = (t >= o) ? s[t - o] : 0;
        __syncthreads();
        if (t >= o) s[t] += u;
        __syncthreads();
    }
    if (i < NN) offs[i] = s[t] - v;
    if (t == 255) part[blockIdx.x] = s[255];
}

__global__ __launch_bounds__(256)
void k_scan2(int* __restrict__ part) {
    __shared__ int s[256];
    int t = threadIdx.x;
    int v = (t < NBLK) ? part[t] : 0;
    s[t] = v;
    __syncthreads();
#pragma unroll
    for (int o = 1; o < 256; o <<= 1) {
        int u = (t >= o) ? s[t - o] : 0;
        __syncthreads();
        if (t >= o) s[t] += u;
        __syncthreads();
    }
    if (t < NBLK) part[t] = s[t] - v;
}

__global__ __launch_bounds__(256)
void k_scan3(int* __restrict__ offs, const int* __restrict__ part) {
    int i = blockIdx.x * 256 + threadIdx.x;
    if (i < NN) offs[i] += part[i >> 8];
}

// ------- edge MLP, cooperative octet layout: 8 lanes per edge ---------------
// Octet leader gathers offs[dst] AND eh4[src] (both L2-resident, independent),
// folds eh into z, scatters rec = {src, w01(f16), w23(f16), 0}.
__global__ __launch_bounds__(256)
void k_logit8(const float* __restrict__ edge_attr, const int* __restrict__ dst,
              const int* __restrict__ src, const float* __restrict__ w_ee,
              const int* __restrict__ offs, const int* __restrict__ rank,
              const float4* __restrict__ eh4, i32x4* __restrict__ rec4) {
    int tid = threadIdx.x;
    int wave = tid >> 6, lane = tid & 63;
    long wbase = (long)blockIdx.x * 256 + wave * 64;   // first edge of this wave
    int dv = dst[wbase + lane];
    int rv = rank[wbase + lane];
    int sv = src[wbase + lane];
    int oct = lane >> 3;        // edge slot within a pass (0..7)
    int ol  = lane & 7;         // dim slot within edge (4 floats each)
    float wr[NH][4];
#pragma unroll
    for (int h = 0; h < NH; ++h) {
        f32x4 wv = *(const f32x4*)(w_ee + h * EDD + ol * 4);
        wr[h][0] = wv[0]; wr[h][1] = wv[1]; wr[h][2] = wv[2]; wr[h][3] = wv[3];
    }
    f32x4 u[8];
    const f32x4* ea = (const f32x4*)(edge_attr + wbase * EDD);
#pragma unroll
    for (int p = 0; p < 8; ++p) u[p] = ea[p * 64 + lane];
    asm volatile("" ::: "memory");
#pragma unroll
    for (int p = 0; p < 8; ++p) {
        float z[NH];
#pragma unroll
        for (int h = 0; h < NH; ++h)
            z[h] = u[p][0] * wr[h][0] + u[p][1] * wr[h][1]
                 + u[p][2] * wr[h][2] + u[p][3] * wr[h][3];
#pragma unroll
        for (int h = 0; h < NH; ++h) {      // octet butterfly reduce
            z[h] += __shfl_xor(z[h], 1);
            z[h] += __shfl_xor(z[h], 2);
            z[h] += __shfl_xor(z[h], 4);
        }
        int ei   = p * 8 + oct;             // edge slot within wave
        int lsrc = __shfl(sv, ei);
        int ld   = __shfl(dv, ei);
        int lr   = __shfl(rv, ei);
        if (ol == 0) {                      // leader: 2 indep gathers + scatter
            int pos = offs[ld] + lr;        // L2-hot 0.2MB
            float4 ehv = eh4[lsrc];         // L2-hot 0.8MB, independent
            h2i w01, w23;
            w01.h[0] = (_Float16)(z[0] + ehv.x);
            w01.h[1] = (_Float16)(z[1] + ehv.y);
            w23.h[0] = (_Float16)(z[2] + ehv.z);
            w23.h[1] = (_Float16)(z[3] + ehv.w);
            i32x4 rc = {lsrc, w01.i, w23.i, 0};
            rec4[pos] = rc;
        }
    }
}

// ------- per-dst reduce: coalesced rec read (carries src + z+eh) ------------
__global__ __launch_bounds__(256)
void k_reduce(const int* __restrict__ offs, const int* __restrict__ deg,
              const i32x4* __restrict__ rec4,
              const float* __restrict__ et,
              const _Float16* __restrict__ feat_h, const float* __restrict__ bias,
              float* __restrict__ out) {
    int wid = (blockIdx.x * 256 + threadIdx.x) >> 6;   // one wave per dst node
    int lane = threadIdx.x & 63;
    if (wid >= NN) return;
    int start = __builtin_amdgcn_readfirstlane(offs[wid]);
    int dn    = __builtin_amdgcn_readfirstlane(deg[wid]);
    int h = lane >> 4;          // head of this lane
    int q = lane & 15;          // edge slot within chunk
    float et_h = et[(long)wid * 4 + h];                // wave-level uniform
    float acc = 0.f, l = 0.f;

    for (int c0 = 0; c0 < dn; c0 += 16) {
        int rem = dn - c0; if (rem > 16) rem = 16;
        int qq = (q < rem) ? q : (rem - 1);            // clamp: stay in-bounds
        i32x4 r = rec4[start + c0 + qq];               // COALESCED 256B/wave
        int   s_q = r.x;
        h2i u; u.i = (h & 2) ? r.z : r.y;
        float x = (float)u.h[h & 1] + et_h;            // w = z+eh already folded
        x = x > 0.f ? x : NEG_SLOPE * x;
        float a_q = (q < rem) ? __expf(x) : 0.f;       // no max-shift: 0.1-scale
        float f[16];
#pragma unroll
        for (int i = 0; i < 16; ++i) {
            int si = __shfl(s_q, i);                   // edge i's src (quad 0)
            f[i] = (float)feat_h[(long)si * HD + lane]; // coalesced 128B row gather
        }
#pragma unroll
        for (int i = 0; i < 16; ++i) {
            float ai = __shfl(a_q, (lane & 48) + i);   // edge i, this lane's head
            l += ai;
            acc += ai * f[i];
        }
    }
    float res = (l > 0.f) ? acc / l : 0.f;
    __builtin_nontemporal_store(res + bias[lane], &out[(long)wid * HD + lane]);
}

extern "C" void kernel_launch(void* const* d_in, const int* in_sizes, int n_in,
                              void* d_out, int out_size, void* d_ws, size_t ws_size,
                              hipStream_t stream) {
    const float* feat      = (const float*)d_in[0];
    const float* edge_attr = (const float*)d_in[1];
    const int*   src       = (const int*)d_in[2];
    const int*   dst       = (const int*)d_in[3];
    const float* W_fc      = (const float*)d_in[4];
    const float* W_edge    = (const float*)d_in[5];
    const float* attn_h    = (const float*)d_in[6];
    const float* attn_t    = (const float*)d_in[7];
    const float* attn_e    = (const float*)d_in[8];
    const float* bias      = (const float*)d_in[9];
    float* out             = (float*)d_out;

    float* ws        = (float*)d_ws;
    i32x4*  rec4     = (i32x4*)ws;                     // E*16B (12.8 MB)
    float4* eh4      = (float4*)(rec4 + EE);           // N*4
    float4* et4      = eh4 + NN;                       // N*4
    _Float16* feat_h = (_Float16*)(et4 + NN);          // N*64 halves (6.4 MB)
    float*  Wt       = (float*)(feat_h + (long)NN * HD); // 8192
    float*  w_ee     = Wt + HD * IND;                  // 128
    int*    rank     = (int*)(w_ee + NH * EDD);        // E
    int*    deg      = rank + EE;                      // N
    int*    offs     = deg + NN;                       // N
    int*    part     = offs + NN;                      // NBLK
    // total ~ 26 MB of d_ws

    k_init_prep<<<NBLK, 256, 0, stream>>>(deg, W_fc, W_edge, attn_e, Wt, w_ee);
    k_node<<<NODE_BLKS, 256, 0, stream>>>(feat, Wt, attn_h, attn_t, feat_h,
                                          (float*)eh4, (float*)et4);
    k_hist<<<(EE + 255) / 256, 256, 0, stream>>>(dst, deg, rank);
    k_scan1<<<NBLK, 256, 0, stream>>>(deg, offs, part);
    k_scan2<<<1, 256, 0, stream>>>(part);
    k_scan3<<<NBLK, 256, 0, stream>>>(offs, part);
    k_logit8<<<EE / 256, 256, 0, stream>>>(edge_attr, dst, src, w_ee,
                                           offs, rank, eh4, rec4);
    k_reduce<<<(NN * 64 + 255) / 256, 256, 0, stream>>>(offs, deg, rec4,
                                                        (const float*)et4,
                                                        feat_h, bias, out);
}

// Round 12
// 310.370 us; speedup vs baseline: 1.1460x; 1.1460x over previous
//
#include <hip/hip_runtime.h>

#define NN 50000
#define EE 800000
#define IND 128
#define EDD 32
#define ODD 16
#define NH 4
#define HD 64
#define NEG_SLOPE 0.2f
#define NBLK ((NN + 255) / 256)   // 196 scan blocks
#define NODE_BLKS ((NN + 63) / 64) // 782 node blocks

typedef float  f32x4 __attribute__((ext_vector_type(4)));
typedef int    i32x2 __attribute__((ext_vector_type(2)));
typedef int    i32x4 __attribute__((ext_vector_type(4)));
typedef _Float16 f16x8 __attribute__((ext_vector_type(8)));

union h2i { int i; _Float16 h[2]; };

// ---------------- init+prep fused: deg=0; Wt transpose; w_ee fold ----------
__global__ __launch_bounds__(256)
void k_init_prep(int* __restrict__ deg, const float* __restrict__ W_fc,
                 const float* __restrict__ W_edge, const float* __restrict__ attn_e,
                 float* __restrict__ Wt, float* __restrict__ w_ee) {
    int i = blockIdx.x * 256 + threadIdx.x;
    if (i < NN) deg[i] = 0;
    if (i < HD * IND) {
        int k = i >> 6, j = i & 63;
        Wt[i] = W_fc[j * IND + k];
    }
    if (i < NH * EDD) {
        int h = i >> 5, k = i & 31;
        float s = 0.f;
        for (int d = 0; d < ODD; ++d)
            s += W_edge[(h * ODD + d) * EDD + k] * attn_e[h * ODD + d];
        w_ee[i] = s;
    }
}

// ------- node projection, LDS-staged cooperative ----------------------------
// Block = 64 rows (32KB LDS), coalesced nt staging (feat read ONCE).
// Thread t = row (t&63) x head (t>>6). CRITICAL: head index forced to SGPR
// via readfirstlane -> weight/attn reads are s_load (round-11 bug: t>>6 was
// unprovably uniform -> 2048 per-lane global loads/thread, 71us).
__global__ __launch_bounds__(256)
void k_node(const float* __restrict__ feat, const float* __restrict__ Wt,
            const float* __restrict__ attn_h, const float* __restrict__ attn_t,
            _Float16* __restrict__ feat_h, float* __restrict__ eh,
            float* __restrict__ et) {
    __shared__ f32x4 buf[64 * 32];          // 32 KB
    int t = threadIdx.x;
    long n0 = (long)blockIdx.x * 64;
    int nrow = (n0 + 64 <= NN) ? 64 : (int)(NN - n0);
    int totj = nrow * 32;
    const f32x4* g = (const f32x4*)feat + n0 * 32;
#pragma unroll
    for (int i = 0; i < 8; ++i) {
        int j = t + i * 256;
        if (j < totj) {
            f32x4 v = __builtin_nontemporal_load(g + j);
            int r = j >> 5, c = j & 31;
            buf[r * 32 + (c ^ (r & 7))] = v;
        }
    }
    __syncthreads();
    int r = t & 63;
    int qt = __builtin_amdgcn_readfirstlane(t >> 6);   // SGPR head -> s_load
    if (n0 + r >= NN) return;
    const int jbase = qt * 16;
    f32x4 row[32];
#pragma unroll
    for (int q = 0; q < 32; ++q) row[q] = buf[r * 32 + (q ^ (r & 7))];
    float acc[16];
#pragma unroll
    for (int j = 0; j < 16; ++j) acc[j] = 0.f;
#pragma unroll
    for (int k0 = 0; k0 < 32; ++k0) {
        float f[4] = {row[k0][0], row[k0][1], row[k0][2], row[k0][3]};
#pragma unroll
        for (int kk = 0; kk < 4; ++kk) {
            const float* w = Wt + (k0 * 4 + kk) * HD + jbase;  // SGPR base
#pragma unroll
            for (int j = 0; j < 16; ++j) acc[j] += f[kk] * w[j];
        }
    }
    long n = n0 + r;
    // fp16 pack: 16 halves = 2 x 16B stores
    f16x8* d8 = (f16x8*)(feat_h + n * HD + jbase);
#pragma unroll
    for (int q = 0; q < 2; ++q) {
        f16x8 v;
#pragma unroll
        for (int j = 0; j < 8; ++j) v[j] = (_Float16)acc[q * 8 + j];
        d8[q] = v;
    }
    float sh = 0.f, st = 0.f;
#pragma unroll
    for (int d = 0; d < ODD; ++d) {
        sh += acc[d] * attn_h[qt * ODD + d];           // s_load
        st += acc[d] * attn_t[qt * ODD + d];
    }
    eh[n * 4 + qt] = sh;                    // [N][4] layout
    et[n * 4 + qt] = st;
}

// ---------------- histogram of dst + per-edge rank --------------------------
__global__ __launch_bounds__(256)
void k_hist(const int* __restrict__ dst, int* __restrict__ deg, int* __restrict__ rank) {
    int e = blockIdx.x * 256 + threadIdx.x;
    if (e < EE) rank[e] = atomicAdd(&deg[dst[e]], 1);
}

// ---------------- two-level exclusive scan of deg -> offs -------------------
__global__ __launch_bounds__(256)
void k_scan1(const int* __restrict__ deg, int* __restrict__ offs, int* __restrict__ part) {
    __shared__ int s[256];
    int t = threadIdx.x, i = blockIdx.x * 256 + t;
    int v = (i < NN) ? deg[i] : 0;
    s[t] = v;
    __syncthreads();
#pragma unroll
    for (int o = 1; o < 256; o <<= 1) {
        int u = (t >= o) ? s[t - o] : 0;
        __syncthreads();
        if (t >= o) s[t] += u;
        __syncthreads();
    }
    if (i < NN) offs[i] = s[t] - v;
    if (t == 255) part[blockIdx.x] = s[255];
}

__global__ __launch_bounds__(256)
void k_scan2(int* __restrict__ part) {
    __shared__ int s[256];
    int t = threadIdx.x;
    int v = (t < NBLK) ? part[t] : 0;
    s[t] = v;
    __syncthreads();
#pragma unroll
    for (int o = 1; o < 256; o <<= 1) {
        int u = (t >= o) ? s[t - o] : 0;
        __syncthreads();
        if (t >= o) s[t] += u;
        __syncthreads();
    }
    if (t < NBLK) part[t] = s[t] - v;
}

__global__ __launch_bounds__(256)
void k_scan3(int* __restrict__ offs, const int* __restrict__ part) {
    int i = blockIdx.x * 256 + threadIdx.x;
    if (i < NN) offs[i] += part[i >> 8];
}

// ------- edge MLP, cooperative octet layout: 8 lanes per edge ---------------
// Octet leader gathers offs[dst] AND eh4[src] (both L2-resident, independent),
// folds eh into z, scatters rec = {src, w01(f16), w23(f16), 0}.
__global__ __launch_bounds__(256)
void k_logit8(const float* __restrict__ edge_attr, const int* __restrict__ dst,
              const int* __restrict__ src, const float* __restrict__ w_ee,
              const int* __restrict__ offs, const int* __restrict__ rank,
              const float4* __restrict__ eh4, i32x4* __restrict__ rec4) {
    int tid = threadIdx.x;
    int wave = tid >> 6, lane = tid & 63;
    long wbase = (long)blockIdx.x * 256 + wave * 64;   // first edge of this wave
    int dv = dst[wbase + lane];
    int rv = rank[wbase + lane];
    int sv = src[wbase + lane];
    int oct = lane >> 3;        // edge slot within a pass (0..7)
    int ol  = lane & 7;         // dim slot within edge (4 floats each)
    float wr[NH][4];
#pragma unroll
    for (int h = 0; h < NH; ++h) {
        f32x4 wv = *(const f32x4*)(w_ee + h * EDD + ol * 4);
        wr[h][0] = wv[0]; wr[h][1] = wv[1]; wr[h][2] = wv[2]; wr[h][3] = wv[3];
    }
    f32x4 u[8];
    const f32x4* ea = (const f32x4*)(edge_attr + wbase * EDD);
#pragma unroll
    for (int p = 0; p < 8; ++p) u[p] = ea[p * 64 + lane];
    asm volatile("" ::: "memory");
#pragma unroll
    for (int p = 0; p < 8; ++p) {
        float z[NH];
#pragma unroll
        for (int h = 0; h < NH; ++h)
            z[h] = u[p][0] * wr[h][0] + u[p][1] * wr[h][1]
                 + u[p][2] * wr[h][2] + u[p][3] * wr[h][3];
#pragma unroll
        for (int h = 0; h < NH; ++h) {      // octet butterfly reduce
            z[h] += __shfl_xor(z[h], 1);
            z[h] += __shfl_xor(z[h], 2);
            z[h] += __shfl_xor(z[h], 4);
        }
        int ei   = p * 8 + oct;             // edge slot within wave
        int lsrc = __shfl(sv, ei);
        int ld   = __shfl(dv, ei);
        int lr   = __shfl(rv, ei);
        if (ol == 0) {                      // leader: 2 indep gathers + scatter
            int pos = offs[ld] + lr;        // L2-hot 0.2MB
            float4 ehv = eh4[lsrc];         // L2-hot 0.8MB, independent
            h2i w01, w23;
            w01.h[0] = (_Float16)(z[0] + ehv.x);
            w01.h[1] = (_Float16)(z[1] + ehv.y);
            w23.h[0] = (_Float16)(z[2] + ehv.z);
            w23.h[1] = (_Float16)(z[3] + ehv.w);
            i32x4 rc = {lsrc, w01.i, w23.i, 0};
            rec4[pos] = rc;
        }
    }
}

// ------- per-dst reduce: coalesced rec read (carries src + z+eh) ------------
__global__ __launch_bounds__(256)
void k_reduce(const int* __restrict__ offs, const int* __restrict__ deg,
              const i32x4* __restrict__ rec4,
              const float* __restrict__ et,
              const _Float16* __restrict__ feat_h, const float* __restrict__ bias,
              float* __restrict__ out) {
    int wid = (blockIdx.x * 256 + threadIdx.x) >> 6;   // one wave per dst node
    int lane = threadIdx.x & 63;
    if (wid >= NN) return;
    int start = __builtin_amdgcn_readfirstlane(offs[wid]);
    int dn    = __builtin_amdgcn_readfirstlane(deg[wid]);
    int h = lane >> 4;          // head of this lane
    int q = lane & 15;          // edge slot within chunk
    float et_h = et[(long)wid * 4 + h];                // wave-level uniform
    float acc = 0.f, l = 0.f;

    for (int c0 = 0; c0 < dn; c0 += 16) {
        int rem = dn - c0; if (rem > 16) rem = 16;
        int qq = (q < rem) ? q : (rem - 1);            // clamp: stay in-bounds
        i32x4 r = rec4[start + c0 + qq];               // COALESCED 256B/wave
        int   s_q = r.x;
        h2i u; u.i = (h & 2) ? r.z : r.y;
        float x = (float)u.h[h & 1] + et_h;            // w = z+eh already folded
        x = x > 0.f ? x : NEG_SLOPE * x;
        float a_q = (q < rem) ? __expf(x) : 0.f;       // no max-shift: 0.1-scale
        float f[16];
#pragma unroll
        for (int i = 0; i < 16; ++i) {
            int si = __shfl(s_q, i);                   // edge i's src (quad 0)
            f[i] = (float)feat_h[(long)si * HD + lane]; // coalesced 128B row gather
        }
#pragma unroll
        for (int i = 0; i < 16; ++i) {
            float ai = __shfl(a_q, (lane & 48) + i);   // edge i, this lane's head
            l += ai;
            acc += ai * f[i];
        }
    }
    float res = (l > 0.f) ? acc / l : 0.f;
    __builtin_nontemporal_store(res + bias[lane], &out[(long)wid * HD + lane]);
}

extern "C" void kernel_launch(void* const* d_in, const int* in_sizes, int n_in,
                              void* d_out, int out_size, void* d_ws, size_t ws_size,
                              hipStream_t stream) {
    const float* feat      = (const float*)d_in[0];
    const float* edge_attr = (const float*)d_in[1];
    const int*   src       = (const int*)d_in[2];
    const int*   dst       = (const int*)d_in[3];
    const float* W_fc      = (const float*)d_in[4];
    const float* W_edge    = (const float*)d_in[5];
    const float* attn_h    = (const float*)d_in[6];
    const float* attn_t    = (const float*)d_in[7];
    const float* attn_e    = (const float*)d_in[8];
    const float* bias      = (const float*)d_in[9];
    float* out             = (float*)d_out;

    float* ws        = (float*)d_ws;
    i32x4*  rec4     = (i32x4*)ws;                     // E*16B (12.8 MB)
    float4* eh4      = (float4*)(rec4 + EE);           // N*4
    float4* et4      = eh4 + NN;                       // N*4
    _Float16* feat_h = (_Float16*)(et4 + NN);          // N*64 halves (6.4 MB)
    float*  Wt       = (float*)(feat_h + (long)NN * HD); // 8192
    float*  w_ee     = Wt + HD * IND;                  // 128
    int*    rank     = (int*)(w_ee + NH * EDD);        // E
    int*    deg      = rank + EE;                      // N
    int*    offs     = deg + NN;                       // N
    int*    part     = offs + NN;                      // NBLK
    // total ~ 26 MB of d_ws

    k_init_prep<<<NBLK, 256, 0, stream>>>(deg, W_fc, W_edge, attn_e, Wt, w_ee);
    k_node<<<NODE_BLKS, 256, 0, stream>>>(feat, Wt, attn_h, attn_t, feat_h,
                                          (float*)eh4, (float*)et4);
    k_hist<<<(EE + 255) / 256, 256, 0, stream>>>(dst, deg, rank);
    k_scan1<<<NBLK, 256, 0, stream>>>(deg, offs, part);
    k_scan2<<<1, 256, 0, stream>>>(part);
    k_scan3<<<NBLK, 256, 0, stream>>>(offs, part);
    k_logit8<<<EE / 256, 256, 0, stream>>>(edge_attr, dst, src, w_ee,
                                           offs, rank, eh4, rec4);
    k_reduce<<<(NN * 64 + 255) / 256, 256, 0, stream>>>(offs, deg, rec4,
                                                        (const float*)et4,
                                                        feat_h, bias, out);
}